// Round 1
// baseline (43.628 us; speedup 1.0000x reference)
//
#include <hip/hip_runtime.h>

// ---------------------------------------------------------------------------
// Problem: out[b,n,m] = sum_e relu(px[b,n,e] + pyc[b,m,e]) * w[e] + ob
//   coeff[b,e] = tanh(weights[b,:] . A_w[e,:] + A_b[e])
//   px[b,n,e]  = sum_d X[b,n,d]*coeff[b,d]*lin_w[e,d]
//   pyc[b,m,e] = sum_d Y[b,m,d]*lin_w[e,128+d] + lin_b[e]
// Trick: relu(u) = (u+|u|)/2  =>
//   out = qx[n] + qy[m] + sum_e (w[e]/2)*|px+pyc| + ob
//   qx[n] = sum_e (w[e]/2)*px[n,e], qy[m] = sum_e (w[e]/2)*pyc[m,e]
// ---------------------------------------------------------------------------

#define B_ 8
#define NM 256
#define D_ 128
#define DIN 1024

// K1: coeff[b][e], one wave per (b,e). grid 256 x 256thr.
__global__ void k_coeff(const float* __restrict__ W, const float* __restrict__ Aw,
                        const float* __restrict__ Ab, float* __restrict__ coeff) {
    int wid  = (blockIdx.x * blockDim.x + threadIdx.x) >> 6;  // 0..1023
    int lane = threadIdx.x & 63;
    int b = wid >> 7, e = wid & 127;
    const float4* wr = (const float4*)(W + b * DIN);
    const float4* ar = (const float4*)(Aw + e * DIN);
    float s = 0.f;
#pragma unroll
    for (int i = 0; i < 4; ++i) {
        float4 wv = wr[i * 64 + lane];
        float4 av = ar[i * 64 + lane];
        s += wv.x * av.x + wv.y * av.y + wv.z * av.z + wv.w * av.w;
    }
#pragma unroll
    for (int d = 32; d; d >>= 1) s += __shfl_xor(s, d, 64);
    if (lane == 0) coeff[b * 128 + e] = tanhf(s + Ab[e]);
}

// K2: px / pyc projection GEMMs + qx/qy epilogue.
// grid: x = row tile (16 tiles of 16 rows), y = b*2+src (16). block 128.
// micro: 4 rows (rr + 4i) x 4 e (per phase 2: e = p*64 + er + 32j)
__global__ __launch_bounds__(128) void k_proj(
    const float* __restrict__ X, const float* __restrict__ Y,
    const float* __restrict__ lin_w, const float* __restrict__ lin_b,
    const float* __restrict__ out_w, const float* __restrict__ coeff,
    float* __restrict__ px, float* __restrict__ pyc,
    float* __restrict__ qx, float* __restrict__ qy) {
    __shared__ float S[16][128];      // source rows (coeff-scaled for X)
    __shared__ float Wl[64 * 132];    // 64 e-rows, padded stride 132

    const int bsrc = blockIdx.y, b = bsrc >> 1, src = bsrc & 1;
    const int r0 = blockIdx.x * 16;
    const int t = threadIdx.x;

    // stage S: 16x128 f32 = 512 float4
    const float* Sg = (src ? Y : X) + (size_t)(b * NM + r0) * D_;
    const float* cf = coeff + b * 128;
    for (int i = t; i < 512; i += 128) {
        float4 v = ((const float4*)Sg)[i];
        if (!src) {
            int d = (i & 31) * 4;
            v.x *= cf[d]; v.y *= cf[d + 1]; v.z *= cf[d + 2]; v.w *= cf[d + 3];
        }
        *(float4*)(&S[i >> 5][(i & 31) * 4]) = v;
    }

    const int er = t & 31, rr = t >> 5;          // er 0..31, rr 0..3
    float qpart[4] = {0.f, 0.f, 0.f, 0.f};
    float* Pg = (src ? pyc : px) + (size_t)(b * NM + r0) * D_;

    for (int p = 0; p < 2; ++p) {
        if (p) __syncthreads();
        // stage 64 W rows: lin_w[p*64+e][src*128 + d]
        for (int i = t; i < 64 * 32; i += 128) {
            int e = i >> 5, dq = i & 31;
            *(float4*)(&Wl[e * 132 + dq * 4]) =
                *(const float4*)(lin_w + (size_t)(p * 64 + e) * 256 + src * 128 + dq * 4);
        }
        __syncthreads();

        float acc[4][2] = {};
        for (int k = 0; k < 128; k += 4) {
            float4 a[4], w[2];
#pragma unroll
            for (int i = 0; i < 4; ++i) a[i] = *(const float4*)(&S[rr + 4 * i][k]);
#pragma unroll
            for (int j = 0; j < 2; ++j) w[j] = *(const float4*)(&Wl[(er + 32 * j) * 132 + k]);
#pragma unroll
            for (int i = 0; i < 4; ++i)
#pragma unroll
                for (int j = 0; j < 2; ++j) {
                    acc[i][j] += a[i].x * w[j].x + a[i].y * w[j].y +
                                 a[i].z * w[j].z + a[i].w * w[j].w;
                }
        }
        // epilogue: bias, store, q partials
#pragma unroll
        for (int i = 0; i < 4; ++i)
#pragma unroll
            for (int j = 0; j < 2; ++j) {
                int e = p * 64 + er + 32 * j;
                float v = acc[i][j];
                if (src) v += lin_b[e];
                Pg[(rr + 4 * i) * D_ + e] = v;
                qpart[i] = fmaf(0.5f * out_w[e], v, qpart[i]);
            }
    }
    // reduce qpart over the 32 er-lanes (contiguous within wave half)
    float* Qg = (src ? qy : qx) + b * NM + r0;
#pragma unroll
    for (int i = 0; i < 4; ++i) {
        float s = qpart[i];
#pragma unroll
        for (int d2 = 16; d2; d2 >>= 1) s += __shfl_xor(s, d2, 64);
        if (er == 0) Qg[rr + 4 * i] = s;
    }
}

// K3: main relu-contraction. grid: x = m-tile(8 of 32), y = n-tile(4 of 64), z = b(8).
// block 128 (2 waves). micro 4x4: n rows = nr + 16i (nr = t>>3), m rows = mr + 8j (mr = t&7)
__global__ __launch_bounds__(128) void k_main(
    const float* __restrict__ px, const float* __restrict__ pyc,
    const float* __restrict__ qx, const float* __restrict__ qy,
    const float* __restrict__ out_w, const float* __restrict__ out_b,
    float* __restrict__ out) {
    __shared__ float PXs[64 * 132];
    __shared__ float PYs[32 * 132];
    __shared__ float WHs[128];
    __shared__ float QXl[64], QYl[32];

    const int b = blockIdx.z, n0 = blockIdx.y * 64, m0 = blockIdx.x * 32;
    const int t = threadIdx.x;

    const float4* pxg = (const float4*)(px + (size_t)(b * NM + n0) * D_);
    for (int i = t; i < 2048; i += 128)
        *(float4*)(&PXs[(i >> 5) * 132 + (i & 31) * 4]) = pxg[i];
    const float4* pyg = (const float4*)(pyc + (size_t)(b * NM + m0) * D_);
    for (int i = t; i < 1024; i += 128)
        *(float4*)(&PYs[(i >> 5) * 132 + (i & 31) * 4]) = pyg[i];
    WHs[t] = (t < 128) ? 0.5f * out_w[t] : 0.f;
    if (t < 64) QXl[t] = qx[b * NM + n0 + t];
    else if (t < 96) QYl[t - 64] = qy[b * NM + m0 + (t - 64)];
    __syncthreads();

    const int nr = t >> 3, mr = t & 7;   // nr 0..15, mr 0..7
    float acc[4][4] = {};
    for (int e = 0; e < 128; e += 4) {
        float4 xa[4], ya[4];
        float4 wv = *(const float4*)(&WHs[e]);
#pragma unroll
        for (int i = 0; i < 4; ++i) xa[i] = *(const float4*)(&PXs[(nr + 16 * i) * 132 + e]);
#pragma unroll
        for (int j = 0; j < 4; ++j) ya[j] = *(const float4*)(&PYs[(mr + 8 * j) * 132 + e]);
#pragma unroll
        for (int i = 0; i < 4; ++i)
#pragma unroll
            for (int j = 0; j < 4; ++j) {
                float t0 = xa[i].x + ya[j].x;
                float t1 = xa[i].y + ya[j].y;
                float t2 = xa[i].z + ya[j].z;
                float t3 = xa[i].w + ya[j].w;
                acc[i][j] = fmaf(fabsf(t0), wv.x, acc[i][j]);
                acc[i][j] = fmaf(fabsf(t1), wv.y, acc[i][j]);
                acc[i][j] = fmaf(fabsf(t2), wv.z, acc[i][j]);
                acc[i][j] = fmaf(fabsf(t3), wv.w, acc[i][j]);
            }
    }
    const float ob = out_b[0];
    float* og = out + (size_t)b * NM * NM;
#pragma unroll
    for (int i = 0; i < 4; ++i) {
        int n = n0 + nr + 16 * i;
        float qn = QXl[nr + 16 * i];
#pragma unroll
        for (int j = 0; j < 4; ++j) {
            int m = m0 + mr + 8 * j;
            og[n * NM + m] = acc[i][j] + qn + QYl[mr + 8 * j] + ob;
        }
    }
}

extern "C" void kernel_launch(void* const* d_in, const int* in_sizes, int n_in,
                              void* d_out, int out_size, void* d_ws, size_t ws_size,
                              hipStream_t stream) {
    const float* X      = (const float*)d_in[0];
    const float* Y      = (const float*)d_in[1];
    const float* wts    = (const float*)d_in[2];
    const float* A_w    = (const float*)d_in[3];
    const float* A_b    = (const float*)d_in[4];
    const float* lin_w  = (const float*)d_in[5];
    const float* lin_b  = (const float*)d_in[6];
    const float* out_w  = (const float*)d_in[7];
    const float* out_b  = (const float*)d_in[8];
    float* out = (float*)d_out;

    float* ws    = (float*)d_ws;
    float* coeff = ws;                    // 1024
    float* px    = coeff + 1024;          // 8*256*128
    float* pyc   = px + B_ * NM * D_;     // 8*256*128
    float* qx    = pyc + B_ * NM * D_;    // 2048
    float* qy    = qx + B_ * NM;          // 2048

    k_coeff<<<256, 256, 0, stream>>>(wts, A_w, A_b, coeff);
    k_proj<<<dim3(16, 16), 128, 0, stream>>>(X, Y, lin_w, lin_b, out_w, coeff,
                                             px, pyc, qx, qy);
    k_main<<<dim3(8, 4, 8), 128, 0, stream>>>(px, pyc, qx, qy, out_w, out_b, out);
}

// Round 2
// 31.410 us; speedup vs baseline: 1.3890x; 1.3890x over previous
//
#include <hip/hip_runtime.h>

// out[b,n,m] = qx[b,n] + qy[b,m] + sum_e (w[e]/2)*|px+pyc| + ob
//   relu(u) = (u+|u|)/2 splits into rank-1 part (qx,qy) + abs part.

#define B_ 8
#define NM 256
#define D_ 128
#define DIN 1024

// K1: coeff[b][e] = tanh(W[b,:].Aw[e,:] + Ab[e]), one wave per (b,e).
__global__ void k_coeff(const float* __restrict__ W, const float* __restrict__ Aw,
                        const float* __restrict__ Ab, float* __restrict__ coeff) {
    int wid  = (blockIdx.x * blockDim.x + threadIdx.x) >> 6;  // 0..1023
    int lane = threadIdx.x & 63;
    int b = wid >> 7, e = wid & 127;
    const float4* wr = (const float4*)(W + b * DIN);
    const float4* ar = (const float4*)(Aw + e * DIN);
    float s = 0.f;
#pragma unroll
    for (int i = 0; i < 4; ++i) {
        float4 wv = wr[i * 64 + lane];
        float4 av = ar[i * 64 + lane];
        s += wv.x * av.x + wv.y * av.y + wv.z * av.z + wv.w * av.w;
    }
#pragma unroll
    for (int d = 32; d; d >>= 1) s += __shfl_xor(s, d, 64);
    if (lane == 0) coeff[b * 128 + e] = tanhf(s + Ab[e]);
}

// K2: px / pyc projection + qx/qy. grid (16 row-tiles, 16 b*src), 128 thr.
// All 128 e-rows staged at once; micro 4 rows x 4 e.
__global__ __launch_bounds__(128) void k_proj(
    const float* __restrict__ X, const float* __restrict__ Y,
    const float* __restrict__ lin_w, const float* __restrict__ lin_b,
    const float* __restrict__ out_w, const float* __restrict__ coeff,
    float* __restrict__ px, float* __restrict__ pyc,
    float* __restrict__ qx, float* __restrict__ qy) {
    __shared__ float S[16][128];      // 8 KB
    __shared__ float Wl[128 * 132];   // 67.6 KB, padded stride

    const int bsrc = blockIdx.y, b = bsrc >> 1, src = bsrc & 1;
    const int r0 = blockIdx.x * 16;
    const int t = threadIdx.x;

    // stage S (coeff-folded for X)
    const float* Sg = (src ? Y : X) + (size_t)(b * NM + r0) * D_;
    const float4* cf4 = (const float4*)(coeff + b * 128);
    for (int i = t; i < 512; i += 128) {
        float4 v = ((const float4*)Sg)[i];
        if (!src) {
            float4 c = cf4[i & 31];
            v.x *= c.x; v.y *= c.y; v.z *= c.z; v.w *= c.w;
        }
        *(float4*)(&S[i >> 5][(i & 31) * 4]) = v;
    }
    // stage all 128 W-rows: lin_w[e][src*128 + d]
    for (int i = t; i < 128 * 32; i += 128) {
        int e = i >> 5, dq = i & 31;
        *(float4*)(&Wl[e * 132 + dq * 4]) =
            *(const float4*)(lin_w + (size_t)e * 256 + src * 128 + dq * 4);
    }
    __syncthreads();

    const int er = t & 31, rr = t >> 5;  // er 0..31, rr 0..3
    float acc[4][4] = {};
    for (int k = 0; k < 128; k += 4) {
        float4 a[4], w[4];
#pragma unroll
        for (int i = 0; i < 4; ++i) a[i] = *(const float4*)(&S[rr + 4 * i][k]);
#pragma unroll
        for (int j = 0; j < 4; ++j) w[j] = *(const float4*)(&Wl[(er + 32 * j) * 132 + k]);
#pragma unroll
        for (int i = 0; i < 4; ++i)
#pragma unroll
            for (int j = 0; j < 4; ++j)
                acc[i][j] += a[i].x * w[j].x + a[i].y * w[j].y +
                             a[i].z * w[j].z + a[i].w * w[j].w;
    }

    float qpart[4] = {0.f, 0.f, 0.f, 0.f};
    float* Pg = (src ? pyc : px) + (size_t)(b * NM + r0) * D_;
#pragma unroll
    for (int i = 0; i < 4; ++i)
#pragma unroll
        for (int j = 0; j < 4; ++j) {
            int e = er + 32 * j;
            float v = acc[i][j];
            if (src) v += lin_b[e];
            Pg[(rr + 4 * i) * D_ + e] = v;
            qpart[i] = fmaf(0.5f * out_w[e], v, qpart[i]);
        }
    float* Qg = (src ? qy : qx) + b * NM + r0;
#pragma unroll
    for (int i = 0; i < 4; ++i) {
        float s = qpart[i];
#pragma unroll
        for (int d2 = 16; d2; d2 >>= 1) s += __shfl_xor(s, d2, 64);
        if (er == 0) Qg[rr + 4 * i] = s;
    }
}

// K3: main |.| contraction with 4-way e-split.
// grid (8 m-tiles, 4 n-tiles, 8 b), 512 thr = 8 waves.
// wave w: eq = w&3 (e-quarter), half = w>>2; slot s = half*64+lane.
// micro 4n x 4m: n rows = nr+16i (nr=s>>3), m rows = mr+8j (mr=s&7).
__global__ __launch_bounds__(512) void k_main(
    const float* __restrict__ px, const float* __restrict__ pyc,
    const float* __restrict__ qx, const float* __restrict__ qy,
    const float* __restrict__ out_w, const float* __restrict__ out_b,
    float* __restrict__ out) {
    __shared__ float PXs[64 * 132];
    __shared__ float PYs[32 * 132];
    __shared__ float RED[48 * 128];   // partials, s-fastest (bank-clean)
    __shared__ float WHs[128];
    __shared__ float QXl[64], QYl[32];

    const int b = blockIdx.z, n0 = blockIdx.y * 64, m0 = blockIdx.x * 32;
    const int t = threadIdx.x;

    const float4* pxg = (const float4*)(px + (size_t)(b * NM + n0) * D_);
    for (int i = t; i < 2048; i += 512)
        *(float4*)(&PXs[(i >> 5) * 132 + (i & 31) * 4]) = pxg[i];
    const float4* pyg = (const float4*)(pyc + (size_t)(b * NM + m0) * D_);
    for (int i = t; i < 1024; i += 512)
        *(float4*)(&PYs[(i >> 5) * 132 + (i & 31) * 4]) = pyg[i];
    if (t < 128) WHs[t] = 0.5f * out_w[t];
    if (t >= 128 && t < 192) QXl[t - 128] = qx[b * NM + n0 + (t - 128)];
    if (t >= 192 && t < 224) QYl[t - 192] = qy[b * NM + m0 + (t - 192)];
    __syncthreads();

    const int w = t >> 6, eq = w & 3, half = w >> 2;
    const int s = half * 64 + (t & 63);
    const int nr = s >> 3, mr = s & 7;
    const int e0 = eq * 32;

    float4 wr[8];
#pragma unroll
    for (int q = 0; q < 8; ++q) wr[q] = *(const float4*)(&WHs[e0 + 4 * q]);

    float acc[4][4] = {};
#pragma unroll
    for (int es = 0; es < 32; es += 4) {
        float4 xa[4], ya[4];
        float4 wv = wr[es >> 2];
#pragma unroll
        for (int i = 0; i < 4; ++i)
            xa[i] = *(const float4*)(&PXs[(nr + 16 * i) * 132 + e0 + es]);
#pragma unroll
        for (int j = 0; j < 4; ++j)
            ya[j] = *(const float4*)(&PYs[(mr + 8 * j) * 132 + e0 + es]);
#pragma unroll
        for (int i = 0; i < 4; ++i)
#pragma unroll
            for (int j = 0; j < 4; ++j) {
                float t0 = xa[i].x + ya[j].x;
                float t1 = xa[i].y + ya[j].y;
                float t2 = xa[i].z + ya[j].z;
                float t3 = xa[i].w + ya[j].w;
                acc[i][j] = fmaf(fabsf(t0), wv.x, acc[i][j]);
                acc[i][j] = fmaf(fabsf(t1), wv.y, acc[i][j]);
                acc[i][j] = fmaf(fabsf(t2), wv.z, acc[i][j]);
                acc[i][j] = fmaf(fabsf(t3), wv.w, acc[i][j]);
            }
    }

    if (eq > 0) {
#pragma unroll
        for (int i = 0; i < 4; ++i)
#pragma unroll
            for (int j = 0; j < 4; ++j)
                RED[((eq - 1) * 16 + i * 4 + j) * 128 + s] = acc[i][j];
    }
    __syncthreads();
    if (eq == 0) {
        const float ob = out_b[0];
        float* og = out + (size_t)b * NM * NM;
#pragma unroll
        for (int i = 0; i < 4; ++i) {
            float qn = QXl[nr + 16 * i];
#pragma unroll
            for (int j = 0; j < 4; ++j) {
                float v = acc[i][j];
#pragma unroll
                for (int p = 0; p < 3; ++p)
                    v += RED[(p * 16 + i * 4 + j) * 128 + s];
                og[(n0 + nr + 16 * i) * NM + m0 + mr + 8 * j] =
                    v + qn + QYl[mr + 8 * j] + ob;
            }
        }
    }
}

extern "C" void kernel_launch(void* const* d_in, const int* in_sizes, int n_in,
                              void* d_out, int out_size, void* d_ws, size_t ws_size,
                              hipStream_t stream) {
    const float* X      = (const float*)d_in[0];
    const float* Y      = (const float*)d_in[1];
    const float* wts    = (const float*)d_in[2];
    const float* A_w    = (const float*)d_in[3];
    const float* A_b    = (const float*)d_in[4];
    const float* lin_w  = (const float*)d_in[5];
    const float* lin_b  = (const float*)d_in[6];
    const float* out_w  = (const float*)d_in[7];
    const float* out_b  = (const float*)d_in[8];
    float* out = (float*)d_out;

    float* ws    = (float*)d_ws;
    float* coeff = ws;                    // 1024
    float* px    = coeff + 1024;          // 8*256*128
    float* pyc   = px + B_ * NM * D_;     // 8*256*128
    float* qx    = pyc + B_ * NM * D_;    // 2048
    float* qy    = qx + B_ * NM;          // 2048

    k_coeff<<<256, 256, 0, stream>>>(wts, A_w, A_b, coeff);
    k_proj<<<dim3(16, 16), 128, 0, stream>>>(X, Y, lin_w, lin_b, out_w, coeff,
                                             px, pyc, qx, qy);
    k_main<<<dim3(8, 4, 8), 512, 0, stream>>>(px, pyc, qx, qy, out_w, out_b, out);
}